// Round 4
// baseline (1040.082 us; speedup 1.0000x reference)
//
#include <hip/hip_runtime.h>

#define WSZ 8
#define NHE 4
#define CH 64
#define NT 64
#define HD 16

typedef unsigned short u16;
typedef __attribute__((ext_vector_type(8))) short short8;
typedef __attribute__((ext_vector_type(4))) short short4v;
typedef __attribute__((ext_vector_type(4))) float float4v;

__device__ __forceinline__ u16 f2bf(float f) {
    unsigned u = __float_as_uint(f);
    u += 0x7fff + ((u >> 16) & 1);   // round-to-nearest-even
    return (u16)(u >> 16);
}
// XOR swizzle for [row][64] bf16 arrays (16B chunks stay intact).
__device__ __forceinline__ int SW(int row, int col) {
    return row * 64 + (col ^ ((row & 7) << 3));
}

#define MFMA(a, b, c) __builtin_amdgcn_mfma_f32_16x16x32_bf16(a, b, c, 0, 0, 0)

// ---------------- prologue: weight bf16 conversion + bias table gather ----------------
// ws layout: qw bf16[192*64] @0 (24576B) | pw bf16[64*64] @24576 (8192B)
//            | BI fp32[h][m][nl][nt] @32768 (65536B)
__global__ void prep(const float* __restrict__ qkvw, const float* __restrict__ projw,
                     const float* __restrict__ rpb,
                     u16* __restrict__ qw, u16* __restrict__ pw, float* __restrict__ BI) {
    int t = blockIdx.x * blockDim.x + threadIdx.x;
    int stride = gridDim.x * blockDim.x;
    for (int i = t; i < 192 * 64; i += stride) qw[i] = f2bf(qkvw[i]);
    for (int i = t; i < 64 * 64; i += stride)  pw[i] = f2bf(projw[i]);
    for (int i = t; i < NHE * 64 * 16 * 4; i += stride) {
        int nt = i & 3, nl = (i >> 2) & 15, m = (i >> 6) & 63, h = (i >> 12) & 3;
        int n = nt * 16 + nl;
        int i1 = m >> 3, j1 = m & 7, i2 = n >> 3, j2 = n & 7;
        BI[i] = rpb[((i1 - i2 + 7) * 15 + (j1 - j2 + 7)) * NHE + h];
    }
}

// ---------------- main: one block per horizontally-adjacent WINDOW PAIR ----------------
// 4 waves cooperate on one window at a time; window 1's x is register-prefetched at
// block start so its HBM latency hides under window 0's compute. Full 64B-line IO.
// LDS 49152B -> 3 blocks/CU.
__global__ __launch_bounds__(256, 3) void win_attn(
    const float* __restrict__ x, const float* __restrict__ nw, const float* __restrict__ nb,
    const u16* __restrict__ qw, const u16* __restrict__ pww, const float* __restrict__ BI,
    const float* __restrict__ ascale, float* __restrict__ out, int B, int H, int W)
{
    const int HWsz = H * W;
    const int npw = W / (2 * WSZ);   // window pairs per row
    const int nwh = H / WSZ;
    const int wp = blockIdx.x;
    const int pwx = wp % npw;
    const int t1 = wp / npw;
    const int wh = t1 % nwh;
    const int b  = t1 / nwh;
    const int ww0 = pwx * 2;

    const int tid  = threadIdx.x;
    const int lane = tid & 63;
    const int wv   = tid >> 6;
    const int q    = lane >> 4;
    const int nl   = lane & 15;

    __shared__ alignas(16) char smem[49152];
    float* XS  = (float*)(smem);              // 16384 B fp32 [64ch][64tok]
    u16*   XN  = (u16*)(smem + 16384);        // 8192 B (later: per-wave P)
    u16*   QO  = (u16*)(smem + 24576);        // 8192 B
    u16*   KS  = (u16*)(smem + 32768);        // 8192 B
    u16*   VS  = (u16*)(smem + 40960);        // 8192 B [ch][tok]
    float* PS  = (float*)(smem + 32768);      // LN scratch (aliases KS, dead then)
    float* PS2 = PS + 256;
    float* MUs = PS + 512;
    float* RSs = PS + 576;

    const int rowbase = (wh * WSZ) * W + ww0 * WSZ;
    const float* xw = x + (size_t)b * CH * HWsz + rowbase;

    // ---- weight fragments, loaded once (bf16, L2-hot) ----
    short8 bq[3][2], wf[2];
    #pragma unroll
    for (int nt3 = 0; nt3 < 3; nt3++) {
        int nt = wv * 3 + nt3;
        #pragma unroll
        for (int kt = 0; kt < 2; kt++)
            bq[nt3][kt] = *(const short8*)&qw[(nt * 16 + nl) * 64 + kt * 32 + q * 8];
    }
    #pragma unroll
    for (int kt = 0; kt < 2; kt++)
        wf[kt] = *(const short8*)&pww[(wv * 16 + nl) * 64 + kt * 32 + q * 8];

    // ---- phase 0: window0 -> XS; window1 -> pf registers (same 64B lines) ----
    float4v pf[4];
    #pragma unroll
    for (int rr = 0; rr < 2; rr++) {
        int r = tid + rr * 256;          // 0..511 : (c = r>>3, i = r&7)
        int c = r >> 3, i = r & 7;
        const float* rp = xw + c * HWsz + i * W;
        float4v a0 = *(const float4v*)(rp);
        float4v a1 = *(const float4v*)(rp + 4);
        *(float4v*)&XS[c * 64 + i * 8]     = a0;
        *(float4v*)&XS[c * 64 + i * 8 + 4] = a1;
        pf[rr * 2]     = *(const float4v*)(rp + 8);
        pf[rr * 2 + 1] = *(const float4v*)(rp + 12);
    }
    __syncthreads();

    const float asc = ascale[0];

    for (int wi = 0; wi < 2; wi++) {
        // ---- LayerNorm over channels ----
        {
            float s = 0.f, s2 = 0.f;
            #pragma unroll
            for (int ci = 0; ci < 16; ci++) {
                float v = XS[(wv * 16 + ci) * 64 + lane];
                s += v; s2 += v * v;
            }
            PS[wv * 64 + lane] = s;
            PS2[wv * 64 + lane] = s2;
        }
        __syncthreads();
        if (tid < 64) {
            float s  = PS[tid]  + PS[64 + tid]  + PS[128 + tid]  + PS[192 + tid];
            float s2 = PS2[tid] + PS2[64 + tid] + PS2[128 + tid] + PS2[192 + tid];
            float mu  = s * (1.f / 64.f);
            float var = s2 * (1.f / 64.f) - mu * mu;
            MUs[tid] = mu;
            RSs[tid] = rsqrtf(var + 1e-5f);
        }
        __syncthreads();
        {
            float mu = MUs[lane], rs = RSs[lane];
            #pragma unroll
            for (int ci = 0; ci < 16; ci++) {
                int c = wv * 16 + ci;
                float v = (XS[c * 64 + lane] - mu) * rs * nw[c] + nb[c];
                XN[SW(lane, c)] = f2bf(v);
            }
        }
        __syncthreads();

        // ---- QKV GEMM: wave wv owns n-tiles 3wv..3wv+2 ----
        {
            short8 afr[4][2];
            #pragma unroll
            for (int mt = 0; mt < 4; mt++)
                #pragma unroll
                for (int kt = 0; kt < 2; kt++) {
                    int m = mt * 16 + nl;
                    int phys = (kt * 4 + q) ^ (m & 7);
                    afr[mt][kt] = *(short8*)&XN[m * 64 + phys * 8];
                }
            #pragma unroll
            for (int nt3 = 0; nt3 < 3; nt3++) {
                int nt = wv * 3 + nt3;
                int which = nt >> 2;             // 0:Q 1:K 2:V (wave-uniform)
                int chb = (nt & 3) * 16 + nl;
                #pragma unroll
                for (int mt = 0; mt < 4; mt++) {
                    float4v acc = {0.f, 0.f, 0.f, 0.f};
                    acc = MFMA(afr[mt][0], bq[nt3][0], acc);
                    acc = MFMA(afr[mt][1], bq[nt3][1], acc);
                    int tok0 = mt * 16 + q * 4;
                    if (which == 0) {
                        #pragma unroll
                        for (int r = 0; r < 4; r++) QO[SW(tok0 + r, chb)] = f2bf(acc[r]);
                    } else if (which == 1) {
                        #pragma unroll
                        for (int r = 0; r < 4; r++) KS[SW(tok0 + r, chb)] = f2bf(acc[r]);
                    } else {
                        short4v pk;
                        pk[0] = (short)f2bf(acc[0]); pk[1] = (short)f2bf(acc[1]);
                        pk[2] = (short)f2bf(acc[2]); pk[3] = (short)f2bf(acc[3]);
                        int pt = tok0 ^ ((chb & 7) << 3);
                        *(short4v*)&VS[chb * 64 + pt] = pk;
                    }
                }
            }
        }
        __syncthreads();

        // ---- attention: wave = head h ----
        {
            const int h = wv;
            u16* Pw = XN + wv * 1024;
            const short8 zero8 = {0, 0, 0, 0, 0, 0, 0, 0};
            short8 kfr[4], vfr[2];
            #pragma unroll
            for (int nt = 0; nt < 4; nt++) {
                if (q < 2) {
                    int n = nt * 16 + nl;
                    int phys = (h * 2 + q) ^ (n & 7);
                    kfr[nt] = *(short8*)&KS[n * 64 + phys * 8];
                } else kfr[nt] = zero8;
            }
            #pragma unroll
            for (int kt = 0; kt < 2; kt++) {
                int c = h * 16 + nl;
                int phys = (kt * 4 + q) ^ (c & 7);
                vfr[kt] = *(short8*)&VS[c * 64 + phys * 8];
            }
            #pragma unroll
            for (int mt = 0; mt < 4; mt++) {
                short8 qf;
                if (q < 2) {
                    int m = mt * 16 + nl;
                    int phys = (h * 2 + q) ^ (m & 7);
                    qf = *(short8*)&QO[m * 64 + phys * 8];
                } else qf = zero8;
                float4v b4[4];
                #pragma unroll
                for (int r = 0; r < 4; r++) {
                    int tokm = mt * 16 + q * 4 + r;
                    b4[r] = *(const float4v*)&BI[((h * 64 + tokm) * 16 + nl) * 4];
                }
                float4v sacc[4];
                #pragma unroll
                for (int nt = 0; nt < 4; nt++) {
                    float4v z = {0.f, 0.f, 0.f, 0.f};
                    sacc[nt] = MFMA(qf, kfr[nt], z);
                }
                float sv[4][4], mx[4], sum[4], inv[4];
                #pragma unroll
                for (int r = 0; r < 4; r++) mx[r] = -1e30f;
                #pragma unroll
                for (int nt = 0; nt < 4; nt++)
                    #pragma unroll
                    for (int r = 0; r < 4; r++) {
                        float s = sacc[nt][r] * 0.25f + b4[r][nt];
                        sv[nt][r] = s;
                        mx[r] = fmaxf(mx[r], s);
                    }
                #pragma unroll
                for (int r = 0; r < 4; r++) {
                    #pragma unroll
                    for (int msk = 1; msk <= 8; msk <<= 1)
                        mx[r] = fmaxf(mx[r], __shfl_xor(mx[r], msk, 64));
                    sum[r] = 0.f;
                }
                #pragma unroll
                for (int nt = 0; nt < 4; nt++)
                    #pragma unroll
                    for (int r = 0; r < 4; r++) {
                        float e = __expf(sv[nt][r] - mx[r]);
                        sv[nt][r] = e;
                        sum[r] += e;
                    }
                #pragma unroll
                for (int r = 0; r < 4; r++) {
                    #pragma unroll
                    for (int msk = 1; msk <= 8; msk <<= 1)
                        sum[r] += __shfl_xor(sum[r], msk, 64);
                    inv[r] = 1.f / sum[r];
                }
                #pragma unroll
                for (int nt = 0; nt < 4; nt++)
                    #pragma unroll
                    for (int r = 0; r < 4; r++)
                        Pw[SW(q * 4 + r, nt * 16 + nl)] = f2bf(sv[nt][r] * inv[r]);
                float4v oacc = {0.f, 0.f, 0.f, 0.f};
                #pragma unroll
                for (int kt = 0; kt < 2; kt++) {
                    int phys = (kt * 4 + q) ^ (nl & 7);
                    short8 pfr = *(short8*)&Pw[nl * 64 + phys * 8];
                    oacc = MFMA(pfr, vfr[kt], oacc);
                }
                #pragma unroll
                for (int r = 0; r < 4; r++)
                    QO[SW(mt * 16 + q * 4 + r, h * 16 + nl)] = f2bf(oacc[r]);
            }
        }
        __syncthreads();

        // ---- proj + residual + store ----
        {
            const int ch = wv * 16 + nl;
            float* outp = out + ((size_t)b * CH + ch) * HWsz + rowbase + wi * 8;
            #pragma unroll
            for (int mt = 0; mt < 4; mt++) {
                float4v yacc = {0.f, 0.f, 0.f, 0.f};
                #pragma unroll
                for (int kt = 0; kt < 2; kt++) {
                    int m = mt * 16 + nl;
                    int phys = (kt * 4 + q) ^ (m & 7);
                    short8 of = *(short8*)&QO[m * 64 + phys * 8];
                    yacc = MFMA(of, wf[kt], yacc);
                }
                int tok0 = mt * 16 + q * 4;
                float4v xr = *(float4v*)&XS[ch * 64 + tok0];
                int i = tok0 >> 3, j = tok0 & 7;
                float4v y;
                y[0] = xr[0] + asc * yacc[0];
                y[1] = xr[1] + asc * yacc[1];
                y[2] = xr[2] + asc * yacc[2];
                y[3] = xr[3] + asc * yacc[3];
                *(float4v*)(outp + i * W + j) = y;
            }
        }

        // ---- swap in prefetched window 1 ----
        if (wi == 0) {
            __syncthreads();   // all phase-4 XS reads done
            int r = tid, c = r >> 3, i = r & 7;
            *(float4v*)&XS[c * 64 + i * 8]     = pf[0];
            *(float4v*)&XS[c * 64 + i * 8 + 4] = pf[1];
            r = tid + 256; c = r >> 3; i = r & 7;
            *(float4v*)&XS[c * 64 + i * 8]     = pf[2];
            *(float4v*)&XS[c * 64 + i * 8 + 4] = pf[3];
            __syncthreads();
        }
    }
}

extern "C" void kernel_launch(void* const* d_in, const int* in_sizes, int n_in,
                              void* d_out, int out_size, void* d_ws, size_t ws_size,
                              hipStream_t stream) {
    const float* x     = (const float*)d_in[0];
    const float* nw    = (const float*)d_in[1];
    const float* nb    = (const float*)d_in[2];
    const float* qkvw  = (const float*)d_in[3];
    const float* projw = (const float*)d_in[4];
    const float* asc   = (const float*)d_in[5];
    const float* rpb   = (const float*)d_in[6];

    u16*   qw = (u16*)d_ws;                       // 24576 B
    u16*   pw = (u16*)((char*)d_ws + 24576);      // 8192 B
    float* BI = (float*)((char*)d_ws + 32768);    // 65536 B

    const int H = 256, W = 256;
    const int B = in_sizes[0] / (CH * H * W);
    const int npairs = B * (H / WSZ) * (W / (2 * WSZ));

    prep<<<128, 256, 0, stream>>>(qkvw, projw, rpb, qw, pw, BI);
    win_attn<<<npairs, 256, 0, stream>>>(x, nw, nb, qw, pw, BI, asc,
                                         (float*)d_out, B, H, W);
}